// Round 6
// baseline (1485.053 us; speedup 1.0000x reference)
//
#include <hip/hip_runtime.h>
#include <stdint.h>

#define M_NODES 100000
#define NUM_EDGES 3200000
#define IN_DIM 512
#define HIDDEN 256
#define NCLS 64

typedef __bf16 bf16x8 __attribute__((ext_vector_type(8)));
typedef float floatx4 __attribute__((ext_vector_type(4)));
typedef unsigned int uintx2 __attribute__((ext_vector_type(2)));
typedef unsigned short ushortx4 __attribute__((ext_vector_type(4)));

// ---- workspace layout (bytes) ----
// rp    : int[100001]            @ 0
// w1t   : ushort[256*512]        @ 400016
// w2t   : ushort[64*256]         @ 662160
// h1    : ushort[100000*256]     @ 694928   (dead after gemm2; carved below)
//   bB   : ushort[4][100000][16] @ 694928   (bf16 T blocked, flip buffer)
//   zblk : float[4][100000][16]  @ 13494928 (blocked z accumulator; ends 39094928 < fA)
// fA    : float[4][100000][16]   @ 51894928 (fp32 T blocked)
// fB    : float[4][100000][16]   @ 77494928
// bA    : ushort[4][100000][16]  @ 103094928
#define WS_ROWPTR 0
#define WS_W1T    400016
#define WS_W2T    662160
#define WS_H1     694928
#define WS_BB     694928
#define WS_ZBLK   13494928
#define WS_FA     51894928
#define WS_FB     77494928
#define WS_BA     103094928

// ---------------- weight transpose + bf16 convert ----------------
__global__ __launch_bounds__(256) void prep_weights(
    const float* __restrict__ W1, const float* __restrict__ W2,
    unsigned short* __restrict__ w1t, unsigned short* __restrict__ w2t) {
  int tid = blockIdx.x * 256 + threadIdx.x;
  if (tid < IN_DIM * HIDDEN) {
    int n = tid >> 9;
    int k = tid & 511;
    __bf16 v = (__bf16)W1[k * HIDDEN + n];
    w1t[tid] = __builtin_bit_cast(unsigned short, v);
  } else {
    int idx = tid - IN_DIM * HIDDEN;
    if (idx < HIDDEN * NCLS) {
      int n = idx >> 8;
      int k = idx & 255;
      __bf16 v = (__bf16)W2[k * NCLS + n];
      w2t[idx] = __builtin_bit_cast(unsigned short, v);
    }
  }
}

// ---------------- row_ptr via binary search over sorted edge_row ----------------
__global__ __launch_bounds__(256) void build_rowptr(
    const int* __restrict__ erow, int* __restrict__ rp) {
  int r = blockIdx.x * 256 + threadIdx.x;
  if (r > M_NODES) return;
  if (r == M_NODES) { rp[r] = NUM_EDGES; return; }
  int lo = 0, hi = NUM_EDGES;
  while (lo < hi) {
    int mid = (lo + hi) >> 1;
    if (erow[mid] < r) lo = mid + 1; else hi = mid;
  }
  rp[r] = lo;
}

// ---------------- GEMM1 (R0 known-good): h1 = relu(x @ W1 + b1) ----------------
__global__ __launch_bounds__(256) void gemm1(
    const float* __restrict__ x, const unsigned short* __restrict__ w1t,
    const float* __restrict__ b1, unsigned short* __restrict__ h1) {
  __shared__ float xs[32 * 68];
  const int wave = threadIdx.x >> 6, lane = threadIdx.x & 63;
  const int m0 = blockIdx.x * 32;
  const int n0 = wave * 64;
  const int l15 = lane & 15, quad = lane >> 4;
  const int t = threadIdx.x;

  floatx4 acc[2][4] = {};
  for (int kb = 0; kb < IN_DIM; kb += 64) {
    __syncthreads();
#pragma unroll
    for (int j = 0; j < 2; j++) {
      const int i = t * 2 + j;      // 0..511
      const int row = i >> 4;       // 0..31
      const int kq = i & 15;        // float4 index within row
      floatx4 v = *(const floatx4*)(x + (size_t)(m0 + row) * IN_DIM + kb + kq * 4);
      *(floatx4*)(xs + row * 68 + kq * 4) = v;
    }
    __syncthreads();

    bf16x8 afrag[2][2];
    bf16x8 bfrag[2][4];
#pragma unroll
    for (int ks = 0; ks < 2; ks++) {
#pragma unroll
      for (int tm = 0; tm < 2; tm++) {
        const float* p = xs + (tm * 16 + l15) * 68 + ks * 32 + quad * 8;
        floatx4 a0 = *(const floatx4*)p;
        floatx4 a1 = *(const floatx4*)(p + 4);
        bf16x8 f;
        f[0] = (__bf16)a0[0]; f[1] = (__bf16)a0[1]; f[2] = (__bf16)a0[2]; f[3] = (__bf16)a0[3];
        f[4] = (__bf16)a1[0]; f[5] = (__bf16)a1[1]; f[6] = (__bf16)a1[2]; f[7] = (__bf16)a1[3];
        afrag[ks][tm] = f;
      }
      const int k = kb + ks * 32 + quad * 8;
#pragma unroll
      for (int tn = 0; tn < 4; tn++)
        bfrag[ks][tn] = *(const bf16x8*)(w1t + (size_t)(n0 + tn * 16 + l15) * IN_DIM + k);
    }
#pragma unroll
    for (int ks = 0; ks < 2; ks++)
#pragma unroll
      for (int tm = 0; tm < 2; tm++)
#pragma unroll
        for (int tn = 0; tn < 4; tn++)
          acc[tm][tn] = __builtin_amdgcn_mfma_f32_16x16x32_bf16(afrag[ks][tm], bfrag[ks][tn], acc[tm][tn], 0, 0, 0);
  }

#pragma unroll
  for (int tm = 0; tm < 2; tm++)
#pragma unroll
    for (int tn = 0; tn < 4; tn++) {
      const int col = n0 + tn * 16 + l15;
      const float bias = b1[col];
#pragma unroll
      for (int r = 0; r < 4; r++) {
        const int row = m0 + tm * 16 + quad * 4 + r;
        float v = acc[tm][tn][r] + bias;
        v = v > 0.0f ? v : 0.0f;
        __bf16 bv = (__bf16)v;
        h1[(size_t)row * HIDDEN + col] = __builtin_bit_cast(unsigned short, bv);
      }
    }
}

// ---------------- GEMM2: T0 = h1 @ W2 + b2 -> BLOCKED fp32 (fA) + bf16 (bA) ----
// Blocked layout [g][node][16]: col = tn*16 + l15 -> group tn, within-col l15.
// Lane stores stay 64B/32B contiguous per (row, group) -- same coalescing.
__global__ __launch_bounds__(256) void gemm2(
    const unsigned short* __restrict__ h1, const unsigned short* __restrict__ w2t,
    const float* __restrict__ b2, float* __restrict__ t0f,
    unsigned short* __restrict__ t0b) {
  const int wave = threadIdx.x >> 6, lane = threadIdx.x & 63;
  const int m0 = blockIdx.x * 128 + wave * 32;
  if (m0 >= M_NODES) return;
  const int l15 = lane & 15, quad = lane >> 4;

  floatx4 acc[2][4] = {};
  for (int kb = 0; kb < HIDDEN; kb += 32) {
    const int k = kb + quad * 8;
    bf16x8 afrag[2], bfrag[4];
#pragma unroll
    for (int tm = 0; tm < 2; tm++)
      afrag[tm] = *(const bf16x8*)(h1 + (size_t)(m0 + tm * 16 + l15) * HIDDEN + k);
#pragma unroll
    for (int tn = 0; tn < 4; tn++)
      bfrag[tn] = *(const bf16x8*)(w2t + (size_t)(tn * 16 + l15) * HIDDEN + k);
#pragma unroll
    for (int tm = 0; tm < 2; tm++)
#pragma unroll
      for (int tn = 0; tn < 4; tn++)
        acc[tm][tn] = __builtin_amdgcn_mfma_f32_16x16x32_bf16(afrag[tm], bfrag[tn], acc[tm][tn], 0, 0, 0);
  }

#pragma unroll
  for (int tm = 0; tm < 2; tm++)
#pragma unroll
    for (int tn = 0; tn < 4; tn++) {
      const int col = tn * 16 + l15;
      const float bias = b2[col];
#pragma unroll
      for (int r = 0; r < 4; r++) {
        const int row = m0 + tm * 16 + quad * 4 + r;
        const float v = acc[tm][tn][r] + bias;
        const size_t bidx = ((size_t)tn * M_NODES + row) * 16 + l15;
        t0f[bidx] = v;
        __bf16 bv = (__bf16)v;
        t0b[bidx] = __builtin_bit_cast(unsigned short, bv);
      }
    }
}

// ---------------- column-blocked, XCD-pinned SpMM step ----------------
// Chebyshev is column-separable: z[:,c] depends only on T[:,c]. Split the 64
// classes into 4 groups of 16; group slice of T-bf16 = 100000*16*2B = 3.2MB
// <= 4MB per-XCD L2. Pin group to an XCD PAIR via the round-robin blockIdx
// mapping: grp = (bid&7)>>1 -> each XCD's L2 only ever gathers one slice,
// which stays resident (hottest lines). Gathers: L3 (~3.5TB/s) -> L2.
// Lane map: g16 = lane&15 edge slot, q = lane>>4 col-quad (4 cols, 8B gather).
// Dual row streams per wave; 4 waves = 8 rows/block; grid = 4 grp * 12500.
__global__ __launch_bounds__(256) void spmm_blk(
    const int* __restrict__ rp, const int* __restrict__ cols,
    const float* __restrict__ vals, const unsigned short* __restrict__ tb,
    const float* __restrict__ tpf, float* __restrict__ pff,
    unsigned short* __restrict__ outb, const float* __restrict__ gamma,
    int kidx, float* __restrict__ zblk) {
  const int bid = blockIdx.x;
  const int grp = (bid & 7) >> 1;
  const int rowblk = (bid >> 3) * 2 + (bid & 1);
  const int wave = threadIdx.x >> 6, lane = threadIdx.x & 63;
  const int g16 = lane & 15, q = lane >> 4;
  const int r0 = rowblk * 8 + wave * 2, r1 = r0 + 1;
  const int gbase = grp * M_NODES;

  const int s0 = rp[r0], e0 = rp[r0 + 1];
  const int s1 = rp[r1], e1 = rp[r1 + 1];
  const int nb0 = (e0 - s0 + 15) >> 4;
  const int nb1 = (e1 - s1 + 15) >> 4;
  const int nb = nb0 > nb1 ? nb0 : nb1;   // wave-uniform

  const char* tbb = (const char*)tb;
  const int qoff = q * 8;

  float a0[4] = {}, a1[4] = {};

#define LDCV(B)                                                            \
  {                                                                        \
    int i0 = s0 + (B) * 16 + g16, i1 = s1 + (B) * 16 + g16;                \
    int idx0 = i0 < e0 ? i0 : (e0 - 1); idx0 = idx0 > 0 ? idx0 : 0;        \
    int idx1 = i1 < e1 ? i1 : (e1 - 1); idx1 = idx1 > 0 ? idx1 : 0;        \
    c0 = cols[idx0]; c1 = cols[idx1];                                      \
    float t0_ = vals[idx0], t1_ = vals[idx1];                              \
    v0 = (i0 < e0) ? t0_ : 0.0f;                                           \
    v1 = (i1 < e1) ? t1_ : 0.0f;                                           \
  }
#define GAT(C) (*(const uintx2*)(tbb + ((size_t)(unsigned)(gbase + (C))) * 32 + qoff))

  if (nb > 0) {
    int c0, c1;
    float v0, v1;
    LDCV(0);
    for (int b = 0; b < nb; ++b) {
      const uintx2 d0 = GAT(c0);
      const uintx2 d1 = GAT(c1);
      const float cv0 = v0, cv1 = v1;
      if (b + 1 < nb) LDCV(b + 1);
#pragma unroll
      for (int j = 0; j < 2; ++j) {
        const unsigned u0 = d0[j], u1 = d1[j];
        a0[2 * j]     += cv0 * __builtin_bit_cast(float, u0 << 16);
        a0[2 * j + 1] += cv0 * __builtin_bit_cast(float, u0 & 0xffff0000u);
        a1[2 * j]     += cv1 * __builtin_bit_cast(float, u1 << 16);
        a1[2 * j + 1] += cv1 * __builtin_bit_cast(float, u1 & 0xffff0000u);
      }
    }
  }
#undef LDCV
#undef GAT

  // reduce over the 16 edge slots (lane bits 0..3); all lanes get full sums
#pragma unroll
  for (int m = 1; m <= 8; m <<= 1) {
#pragma unroll
    for (int j = 0; j < 4; ++j) {
      a0[j] += __shfl_xor(a0[j], m, 64);
      a1[j] += __shfl_xor(a1[j], m, 64);
    }
  }

  // epilogue: lane g16==0 -> r0, g16==1 -> r1 (8 active lanes: 2 rows x 4 quads)
  if (g16 <= 1) {
    const int rr = (g16 == 0) ? r0 : r1;
    float s[4];
#pragma unroll
    for (int j = 0; j < 4; ++j) s[j] = (g16 == 0) ? a0[j] : a1[j];
    const size_t bidx = ((size_t)gbase + rr) * 16 + q * 4;

    floatx4 tn4, z4;
    ushortx4 pk;
    if (kidx == 1) {
      const float g0 = gamma[0], g1 = gamma[1];
      const floatx4 p = *(const floatx4*)(tpf + bidx);
#pragma unroll
      for (int j = 0; j < 4; ++j) {
        tn4[j] = s[j];
        z4[j] = g0 * p[j] + g1 * s[j];
      }
    } else {
      const float gk = gamma[kidx];
      const floatx4 p = *(const floatx4*)(tpf + bidx);
      const floatx4 zp = *(const floatx4*)(zblk + bidx);
#pragma unroll
      for (int j = 0; j < 4; ++j) {
        tn4[j] = 2.0f * s[j] - p[j];
        z4[j] = zp[j] + gk * tn4[j];
      }
    }
#pragma unroll
    for (int j = 0; j < 4; ++j) {
      __bf16 bv = (__bf16)tn4[j];
      pk[j] = __builtin_bit_cast(unsigned short, bv);
    }
    *(floatx4*)(pff + bidx) = tn4;
    *(ushortx4*)(outb + bidx) = pk;
    *(floatx4*)(zblk + bidx) = z4;
  }
}

// ---------------- un-block z: [4][N][16] -> [N][64] ----------------
__global__ __launch_bounds__(256) void unblock_z(
    const float* __restrict__ zblk, float* __restrict__ z) {
  const int tid = blockIdx.x * 256 + threadIdx.x;  // 0 .. 100000*16-1
  const int r = tid >> 4;
  const int idx = tid & 15;
  const int g = idx >> 2, q = idx & 3;
  floatx4 v = *(const floatx4*)(zblk + ((size_t)g * M_NODES + r) * 16 + q * 4);
  *(floatx4*)(z + (size_t)r * 64 + g * 16 + q * 4) = v;
}

extern "C" void kernel_launch(void* const* d_in, const int* in_sizes, int n_in,
                              void* d_out, int out_size, void* d_ws, size_t ws_size,
                              hipStream_t stream) {
  const float* x     = (const float*)d_in[0];
  const int*   erow  = (const int*)d_in[1];
  const int*   ecol  = (const int*)d_in[2];
  const float* evals = (const float*)d_in[3];
  const float* W1    = (const float*)d_in[4];
  const float* b1    = (const float*)d_in[5];
  const float* W2    = (const float*)d_in[6];
  const float* b2    = (const float*)d_in[7];
  const float* gamma = (const float*)d_in[8];

  char* ws = (char*)d_ws;
  int*            rp   = (int*)(ws + WS_ROWPTR);
  unsigned short* w1t  = (unsigned short*)(ws + WS_W1T);
  unsigned short* w2t  = (unsigned short*)(ws + WS_W2T);
  unsigned short* h1   = (unsigned short*)(ws + WS_H1);
  float*          zblk = (float*)(ws + WS_ZBLK);
  float*          fA   = (float*)(ws + WS_FA);
  float*          fB   = (float*)(ws + WS_FB);
  unsigned short* bA   = (unsigned short*)(ws + WS_BA);
  unsigned short* bB   = (unsigned short*)(ws + WS_BB);  // aliases h1 head
  float*          z    = (float*)d_out;

  prep_weights<<<576, 256, 0, stream>>>(W1, W2, w1t, w2t);
  build_rowptr<<<(M_NODES + 256) / 256, 256, 0, stream>>>(erow, rp);
  gemm1<<<M_NODES / 32, 256, 0, stream>>>(x, w1t, b1, h1);
  gemm2<<<(M_NODES + 127) / 128, 256, 0, stream>>>(h1, w2t, b2, fA, bA);

  const int GRID_S = 4 * (M_NODES / 8);   // 50000: 4 groups x 12500 row-blocks

  // step 1: T1 = L T0; z = g0*T0 + g1*T1   (gather bA; read fA; write fB,bB)
  spmm_blk<<<GRID_S, 256, 0, stream>>>(rp, ecol, evals, bA, fA, fB, bB,
                                       gamma, 1, zblk);

  float*          fprev = fA;   // T_{k-2} fp32 (updated in place)
  float*          fothr = fB;
  unsigned short* bcur  = bB;
  unsigned short* bnext = bA;
  for (int k = 2; k <= 8; ++k) {
    spmm_blk<<<GRID_S, 256, 0, stream>>>(rp, ecol, evals, bcur, fprev, fprev,
                                         bnext, gamma, k, zblk);
    float* tf = fprev; fprev = fothr; fothr = tf;
    unsigned short* tb = bcur; bcur = bnext; bnext = tb;
  }

  unblock_z<<<M_NODES * 16 / 256, 256, 0, stream>>>(zblk, z);
}